// Round 1
// baseline (143.516 us; speedup 1.0000x reference)
//
#include <hip/hip_runtime.h>
#include <cstdint>
#include <cstddef>

#define NROWS 100000
#define FIN 512
#define HIDDEN 256
#define NCLS 50

typedef __attribute__((ext_vector_type(8))) short s16x8;
typedef __attribute__((ext_vector_type(8))) unsigned short u16x8;
typedef __attribute__((ext_vector_type(4))) float f32x4;

__device__ __forceinline__ unsigned short f2bf(float f) {
  unsigned int u = __float_as_uint(f);
  u += 0x7fffu + ((u >> 16) & 1u);
  return (unsigned short)(u >> 16);
}

__device__ __forceinline__ void gload_lds16(const void* g, void* l) {
  __builtin_amdgcn_global_load_lds(
      (const __attribute__((address_space(1))) void*)g,
      (__attribute__((address_space(3))) void*)l, 16, 0, 0);
}

// prep: w1t[n][k] = bf16(W1[k][n]) (transposed, [256][512])
//       w2t[c][k] = bf16(W2[k][c]) for c<50 else 0  ([64][256])
__global__ __launch_bounds__(256) void prep_kernel(
    const float* __restrict__ W1, const float* __restrict__ W2,
    unsigned short* __restrict__ w1t, unsigned short* __restrict__ w2t) {
  int b = blockIdx.x, t = threadIdx.x;
  if (b < FIN) {
    w1t[(size_t)t * FIN + b] = f2bf(W1[(size_t)b * HIDDEN + t]);
  } else {
    int c = b - FIN;  // 0..63
    float v = (c < NCLS) ? W2[(size_t)t * NCLS + c] : 0.0f;
    w2t[(size_t)c * HIDDEN + t] = f2bf(v);
  }
}

// GEMM1: h = relu(x @ W1 + b1), h stored bf16 [NROWS][256]
// 128x128 tile, BK=32, 4 waves (2x2), 16x16x32 bf16 MFMA
__global__ __launch_bounds__(256) void gemm1_kernel(
    const float* __restrict__ x, const unsigned short* __restrict__ w1t,
    const float* __restrict__ b1, unsigned short* __restrict__ h) {
  __shared__ unsigned short Als[128 * 32];  // A tile [row][k] bf16
  __shared__ unsigned short Bls[128 * 32];  // B tile [n][k]  bf16 (W1^T rows)

  const int t = threadIdx.x;
  const int bm = blockIdx.x >> 1;
  const int bn = blockIdx.x & 1;

  // A staging geometry: thread covers (row, 16 k's)
  const int arow = t >> 1;
  const int akc = (t & 1) * 16;
  int grow = bm * 128 + arow;
  if (grow > NROWS - 1) grow = NROWS - 1;  // clamp tail (safe duplicate reads)
  const float* xrow = x + (size_t)grow * FIN + akc;

  const int lane = t & 63;
  const int wid = t >> 6;
  const int wr = wid >> 1;
  const int wc = wid & 1;
  const int q = lane & 15;
  const int half = lane >> 4;

  f32x4 acc[4][4];
  const f32x4 z4 = {0.f, 0.f, 0.f, 0.f};
  for (int m = 0; m < 4; ++m)
    for (int n = 0; n < 4; ++n) acc[m][n] = z4;

  float4 pa0, pa1, pa2, pa3;
  {
    const float4* p = (const float4*)(xrow);
    pa0 = p[0]; pa1 = p[1]; pa2 = p[2]; pa3 = p[3];
  }

  for (int k0 = 0; k0 < FIN; k0 += 32) {
    // write prefetched A regs (fp32 -> bf16) to LDS
    u16x8 v0, v1;
    v0[0] = f2bf(pa0.x); v0[1] = f2bf(pa0.y); v0[2] = f2bf(pa0.z); v0[3] = f2bf(pa0.w);
    v0[4] = f2bf(pa1.x); v0[5] = f2bf(pa1.y); v0[6] = f2bf(pa1.z); v0[7] = f2bf(pa1.w);
    v1[0] = f2bf(pa2.x); v1[1] = f2bf(pa2.y); v1[2] = f2bf(pa2.z); v1[3] = f2bf(pa2.w);
    v1[4] = f2bf(pa3.x); v1[5] = f2bf(pa3.y); v1[6] = f2bf(pa3.z); v1[7] = f2bf(pa3.w);
    *(u16x8*)&Als[arow * 32 + akc] = v0;
    *(u16x8*)&Als[arow * 32 + akc + 8] = v1;

    // B tile: async global->LDS, 512 chunks of 16B, lane-linear LDS dest
    {
      int c = t;
      gload_lds16(w1t + (size_t)(bn * 128 + (c >> 2)) * FIN + k0 + (c & 3) * 8,
                  Bls + c * 8);
      c = t + 256;
      gload_lds16(w1t + (size_t)(bn * 128 + (c >> 2)) * FIN + k0 + (c & 3) * 8,
                  Bls + c * 8);
    }
    __syncthreads();

    // prefetch next A k-step (overlaps MFMA below)
    if (k0 + 32 < FIN) {
      const float4* p = (const float4*)(xrow + k0 + 32);
      pa0 = p[0]; pa1 = p[1]; pa2 = p[2]; pa3 = p[3];
    }

    s16x8 af[4], bfr[4];
#pragma unroll
    for (int m = 0; m < 4; ++m)
      af[m] = *(const s16x8*)&Als[(wr * 64 + m * 16 + q) * 32 + half * 8];
#pragma unroll
    for (int n = 0; n < 4; ++n)
      bfr[n] = *(const s16x8*)&Bls[(wc * 64 + n * 16 + q) * 32 + half * 8];
#pragma unroll
    for (int m = 0; m < 4; ++m)
#pragma unroll
      for (int n = 0; n < 4; ++n)
        acc[m][n] = __builtin_amdgcn_mfma_f32_16x16x32_bf16(af[m], bfr[n],
                                                            acc[m][n], 0, 0, 0);
    __syncthreads();
  }

  // epilogue: bias + relu + bf16 store
#pragma unroll
  for (int n = 0; n < 4; ++n) {
    const int col = bn * 128 + wc * 64 + n * 16 + q;
    const float bias = b1[col];
#pragma unroll
    for (int m = 0; m < 4; ++m) {
      const int rb = bm * 128 + wr * 64 + m * 16 + half * 4;
#pragma unroll
      for (int r = 0; r < 4; ++r) {
        const int row = rb + r;
        if (row < NROWS) {
          float v = acc[m][n][r] + bias;
          v = fmaxf(v, 0.0f);
          h[(size_t)row * HIDDEN + col] = f2bf(v);
        }
      }
    }
  }
}

// GEMM2 + bias + log_softmax. 64 rows/block, 4 waves x 16 rows.
// out[row][c] = z[c] - max - log(sum exp(z - max)), c<50
__global__ __launch_bounds__(256) void gemm2_kernel(
    const unsigned short* __restrict__ h, const unsigned short* __restrict__ w2t,
    const float* __restrict__ b2, float* __restrict__ out) {
  __shared__ unsigned short hls[64 * 256];  // 32 KB
  __shared__ unsigned short wls[64 * 256];  // 32 KB
  const int t = threadIdx.x;
  const int lane = t & 63, wid = t >> 6;
  const int q = lane & 15, half = lane >> 4;
  const int r0 = blockIdx.x * 64;

#pragma unroll
  for (int i = 0; i < 8; ++i) {
    int c = t + i * 256;
    gload_lds16(w2t + c * 8, wls + c * 8);
  }
#pragma unroll
  for (int i = 0; i < 8; ++i) {
    int c = t + i * 256;
    int row = r0 + (c >> 5);
    if (row > NROWS - 1) row = NROWS - 1;
    gload_lds16(h + (size_t)row * HIDDEN + (c & 31) * 8, hls + c * 8);
  }
  __syncthreads();

  f32x4 acc[4];
  const f32x4 z4 = {0.f, 0.f, 0.f, 0.f};
#pragma unroll
  for (int n = 0; n < 4; ++n) acc[n] = z4;

#pragma unroll
  for (int ks = 0; ks < HIDDEN; ks += 32) {
    s16x8 af = *(const s16x8*)&hls[(wid * 16 + q) * HIDDEN + ks + half * 8];
#pragma unroll
    for (int n = 0; n < 4; ++n) {
      s16x8 bfr = *(const s16x8*)&wls[(n * 16 + q) * HIDDEN + ks + half * 8];
      acc[n] = __builtin_amdgcn_mfma_f32_16x16x32_bf16(af, bfr, acc[n], 0, 0, 0);
    }
  }

  float bias[4];
#pragma unroll
  for (int n = 0; n < 4; ++n) {
    int c = n * 16 + q;
    bias[n] = (c < NCLS) ? b2[c] : 0.0f;
  }

#pragma unroll
  for (int r = 0; r < 4; ++r) {
    float vals[4];
    float m = -1e30f;
#pragma unroll
    for (int n = 0; n < 4; ++n) {
      int c = n * 16 + q;
      float v = acc[n][r] + bias[n];
      vals[n] = v;
      if (c < NCLS) m = fmaxf(m, v);
    }
    // row's 50 classes live across the 16-lane group: butterfly reduce
    for (int off = 8; off >= 1; off >>= 1)
      m = fmaxf(m, __shfl_xor(m, off, 64));
    float s = 0.f;
#pragma unroll
    for (int n = 0; n < 4; ++n) {
      int c = n * 16 + q;
      if (c < NCLS) s += __expf(vals[n] - m);
    }
    for (int off = 8; off >= 1; off >>= 1)
      s += __shfl_xor(s, off, 64);
    float lz = __logf(s);
    int rowg = r0 + wid * 16 + half * 4 + r;
    if (rowg < NROWS) {
#pragma unroll
      for (int n = 0; n < 4; ++n) {
        int c = n * 16 + q;
        if (c < NCLS) out[(size_t)rowg * NCLS + c] = vals[n] - m - lz;
      }
    }
  }
}

extern "C" void kernel_launch(void* const* d_in, const int* in_sizes, int n_in,
                              void* d_out, int out_size, void* d_ws, size_t ws_size,
                              hipStream_t stream) {
  const float* x  = (const float*)d_in[0];
  // d_in[1] = edge_index: dead code (ALPHA==1.0 makes APPNP the identity)
  const float* W1 = (const float*)d_in[2];
  const float* b1 = (const float*)d_in[3];
  const float* W2 = (const float*)d_in[4];
  const float* b2 = (const float*)d_in[5];
  float* out = (float*)d_out;

  char* ws = (char*)d_ws;
  unsigned short* w1t = (unsigned short*)(ws);                    // 262144 B
  unsigned short* w2t = (unsigned short*)(ws + 262144);           // 32768 B
  unsigned short* hbf = (unsigned short*)(ws + 262144 + 32768);   // 51.2 MB

  prep_kernel<<<FIN + 64, 256, 0, stream>>>(W1, W2, w1t, w2t);
  gemm1_kernel<<<((NROWS + 127) / 128) * 2, 256, 0, stream>>>(x, w1t, b1, hbf);
  gemm2_kernel<<<(NROWS + 63) / 64, 256, 0, stream>>>(hbf, w2t, b2, out);
}